// Round 1
// baseline (213.109 us; speedup 1.0000x reference)
//
#include <hip/hip_runtime.h>
#include <hip/hip_bf16.h>

#define F_FEAT 32
#define D_DIM 64
#define B_SZ 1024
#define EMB 2048
#define P_PAIRS 496
#define OUT_N 512
#define OUT_STRIDE 2560
#define LN_EPS 1e-6f

typedef __attribute__((ext_vector_type(8))) short bf16x8;
typedef __attribute__((ext_vector_type(4))) float f32x4;

__device__ inline ushort f2bf(float f) {
    union { float f; unsigned u; } a; a.f = f;
    unsigned u = a.u;
    unsigned r = (u + 0x7FFFu + ((u >> 16) & 1u)) >> 16;   // RTNE
    return (ushort)r;
}

// ---------- convert x (fp32) -> bf16, 4 elems/thread ----------
__global__ void k_cvt_x(const float* __restrict__ x, ushort* __restrict__ xb) {
    int i = blockIdx.x * blockDim.x + threadIdx.x;
    int base = i * 4;
    float4 v = *reinterpret_cast<const float4*>(x + base);
    ushort4 o;
    o.x = f2bf(v.x); o.y = f2bf(v.y); o.z = f2bf(v.z); o.w = f2bf(v.w);
    *reinterpret_cast<ushort4*>(xb + base) = o;
}

// ---------- convert+transpose Wp[p][d][e] -> Wpt[p][e][d] bf16 ----------
__global__ void k_cvt_wp(const float* __restrict__ Wp, ushort* __restrict__ Wpt) {
    int p = blockIdx.x;
    const float* src = Wp + (size_t)p * 4096;
    ushort* dst = Wpt + (size_t)p * 4096;
    for (int idx = threadIdx.x; idx < 4096; idx += 256) {
        int d = idx >> 6, e = idx & 63;
        dst[e * 64 + d] = f2bf(src[d * 64 + e]);
    }
}

// ---------- SENet branch: squeeze -> MLP -> reweight -> LayerNorm ----------
__global__ __launch_bounds__(512) void k_senet(
        const float* __restrict__ x,
        const float* __restrict__ W1, const float* __restrict__ b1,
        const float* __restrict__ W2, const float* __restrict__ b2,
        const float* __restrict__ ln_s, const float* __restrict__ ln_b,
        float* __restrict__ out) {
    __shared__ float xs[4][EMB];
    __shared__ float zs[4][128];
    __shared__ float a1s[4][32];
    __shared__ float red[2][4][8];
    int t = threadIdx.x;
    int b0 = blockIdx.x * 4;

    // stage 4 rows of x into LDS (float4 coalesced)
    for (int r = 0; r < 4; ++r) {
        const float4* src = reinterpret_cast<const float4*>(x + (size_t)(b0 + r) * EMB);
        float4* dstv = reinterpret_cast<float4*>(&xs[r][0]);
        dstv[t] = src[t];
    }
    __syncthreads();

    // squeeze: per (row, feature, group) max & mean over 32 elems (rotated to avoid bank conflicts)
    if (t < 256) {
        int r = t >> 6, f = (t >> 1) & 31, gg = t & 1;
        const float* base = &xs[r][f * 64 + gg * 32];
        float mx = -INFINITY, sm = 0.f;
        for (int q = 0; q < 32; ++q) {
            float v = base[(q + t) & 31];
            mx = fmaxf(mx, v); sm += v;
        }
        zs[r][f * 4 + gg]     = mx;
        zs[r][f * 4 + 2 + gg] = sm * (1.f / 32.f);
    }
    __syncthreads();

    // a1 = relu(z @ W1 + b1), 4 rows x 32 outputs
    if (t < 128) {
        int r = t >> 5, c = t & 31;
        float acc = b1[c];
        for (int k = 0; k < 128; ++k) acc += zs[r][k] * W1[k * 32 + c];
        a1s[r][c] = fmaxf(acc, 0.f);
    }
    __syncthreads();

    // weights = a1 @ W2 + b2; senet = x*(w+1); LN stats
    float acc[4][4];
#pragma unroll
    for (int r = 0; r < 4; ++r)
#pragma unroll
        for (int u = 0; u < 4; ++u) acc[r][u] = 0.f;

    for (int k = 0; k < 32; ++k) {
        float a0 = a1s[0][k], a1v = a1s[1][k], a2 = a1s[2][k], a3 = a1s[3][k];
#pragma unroll
        for (int u = 0; u < 4; ++u) {
            float wv = W2[k * EMB + t + 512 * u];
            acc[0][u] += a0 * wv; acc[1][u] += a1v * wv;
            acc[2][u] += a2 * wv; acc[3][u] += a3 * wv;
        }
    }
    float ssum[4], ssq[4];
#pragma unroll
    for (int r = 0; r < 4; ++r) { ssum[r] = 0.f; ssq[r] = 0.f; }
#pragma unroll
    for (int r = 0; r < 4; ++r) {
#pragma unroll
        for (int u = 0; u < 4; ++u) {
            int e = t + 512 * u;
            float w = acc[r][u] + b2[e];
            float s = xs[r][e] * (w + 1.0f);
            xs[r][e] = s;
            ssum[r] += s; ssq[r] += s * s;
        }
    }
    int lane = t & 63, w = t >> 6;
#pragma unroll
    for (int r = 0; r < 4; ++r) {
        float a = ssum[r], q = ssq[r];
        for (int off = 32; off; off >>= 1) { a += __shfl_down(a, off); q += __shfl_down(q, off); }
        if (lane == 0) { red[0][r][w] = a; red[1][r][w] = q; }
    }
    __syncthreads();
    float mu[4], rs[4];
#pragma unroll
    for (int r = 0; r < 4; ++r) {
        float a = 0.f, q = 0.f;
#pragma unroll
        for (int i = 0; i < 8; ++i) { a += red[0][r][i]; q += red[1][r][i]; }
        mu[r] = a * (1.f / 2048.f);
        float var = q * (1.f / 2048.f) - mu[r] * mu[r];
        rs[r] = rsqrtf(var + LN_EPS);
    }
#pragma unroll
    for (int r = 0; r < 4; ++r) {
#pragma unroll
        for (int u = 0; u < 4; ++u) {
            int e = t + 512 * u;
            float s = xs[r][e];
            out[(size_t)(b0 + r) * OUT_STRIDE + e] = (s - mu[r]) * rs[r] * ln_s[e] + ln_b[e];
        }
    }
}

// ---------- pair bilinear: dots[b,p] = (x_i^T Wp_p + bp_p) . x_j  via MFMA ----------
__global__ __launch_bounds__(256) void k_dots(
        const ushort* __restrict__ xb, const ushort* __restrict__ Wpt,
        const float* __restrict__ x, const float* __restrict__ bp,
        float* __restrict__ dots) {
    int bt = blockIdx.x & 15;
    int p  = blockIdx.x >> 4;
    // pair (i,j) from linear index p
    int i = 0, rem = p;
    while (rem >= F_FEAT - 1 - i) { rem -= F_FEAT - 1 - i; ++i; }
    int j = i + 1 + rem;

    int wave = threadIdx.x >> 6, lane = threadIdx.x & 63;
    int b0 = bt * 64 + wave * 16;
    int row = lane & 15, kg = lane >> 4;   // A-frag row / k-group; col for C

    // A frags: Xi tile (16 rows x 64 k), lane holds 8 contiguous k at (kg*8 + ks*32)
    bf16x8 afr[2];
#pragma unroll
    for (int ks = 0; ks < 2; ++ks)
        afr[ks] = *reinterpret_cast<const bf16x8*>(
            xb + (size_t)(b0 + row) * EMB + i * 64 + ks * 32 + kg * 8);

    // B frags: Wp_p as B[k, e] read from transposed layout Wpt[p][e][k]
    bf16x8 bfr[4][2];
#pragma unroll
    for (int nt = 0; nt < 4; ++nt)
#pragma unroll
        for (int ks = 0; ks < 2; ++ks)
            bfr[nt][ks] = *reinterpret_cast<const bf16x8*>(
                Wpt + (size_t)p * 4096 + (nt * 16 + row) * 64 + ks * 32 + kg * 8);

    f32x4 acc[4];
#pragma unroll
    for (int nt = 0; nt < 4; ++nt) {
        f32x4 z = {0.f, 0.f, 0.f, 0.f};
        acc[nt] = z;
    }
#pragma unroll
    for (int nt = 0; nt < 4; ++nt) {
        acc[nt] = __builtin_amdgcn_mfma_f32_16x16x32_bf16(afr[0], bfr[nt][0], acc[nt], 0, 0, 0);
        acc[nt] = __builtin_amdgcn_mfma_f32_16x16x32_bf16(afr[1], bfr[nt][1], acc[nt], 0, 0, 0);
    }

    // epilogue: (proj + bp) . xj, reduce over e (cols) via 16-lane butterfly
    int col = row;
    float part[4] = {0.f, 0.f, 0.f, 0.f};
#pragma unroll
    for (int nt = 0; nt < 4; ++nt) {
        float bpv = bp[p * 64 + nt * 16 + col];
#pragma unroll
        for (int r = 0; r < 4; ++r) {
            int brow = b0 + kg * 4 + r;   // C/D: row=(lane>>4)*4+reg
            float xjv = x[(size_t)brow * EMB + j * 64 + nt * 16 + col];
            part[r] += (acc[nt][r] + bpv) * xjv;
        }
    }
#pragma unroll
    for (int r = 0; r < 4; ++r) {
        float v = part[r];
        v += __shfl_xor(v, 1); v += __shfl_xor(v, 2);
        v += __shfl_xor(v, 4); v += __shfl_xor(v, 8);
        part[r] = v;
    }
    if (col == 0) {
#pragma unroll
        for (int r = 0; r < 4; ++r)
            dots[(size_t)(b0 + kg * 4 + r) * P_PAIRS + p] = part[r];
    }
}

// ---------- bilinear head: out[:,2048:] = dots @ Wo + bo ----------
__global__ __launch_bounds__(256) void k_bilinear(
        const float* __restrict__ dots, const float* __restrict__ Wo,
        const float* __restrict__ bo, float* __restrict__ out) {
    __shared__ float ds[8][P_PAIRS];
    int t = threadIdx.x;
    int bb = blockIdx.x >> 1;
    int nn = blockIdx.x & 1;
    int b0 = bb * 8;
    int n = nn * 256 + t;
#pragma unroll
    for (int r = 0; r < 8; ++r)
        for (int k = t; k < P_PAIRS; k += 256)
            ds[r][k] = dots[(size_t)(b0 + r) * P_PAIRS + k];
    __syncthreads();
    float acc[8];
#pragma unroll
    for (int r = 0; r < 8; ++r) acc[r] = 0.f;
    for (int k = 0; k < P_PAIRS; ++k) {
        float wv = Wo[k * OUT_N + n];
#pragma unroll
        for (int r = 0; r < 8; ++r) acc[r] += ds[r][k] * wv;
    }
    float bov = bo[n];
#pragma unroll
    for (int r = 0; r < 8; ++r)
        out[(size_t)(b0 + r) * OUT_STRIDE + 2048 + n] = acc[r] + bov;
}

extern "C" void kernel_launch(void* const* d_in, const int* in_sizes, int n_in,
                              void* d_out, int out_size, void* d_ws, size_t ws_size,
                              hipStream_t stream) {
    const float* x    = (const float*)d_in[0];
    const float* W1   = (const float*)d_in[1];
    const float* b1   = (const float*)d_in[2];
    const float* W2   = (const float*)d_in[3];
    const float* b2   = (const float*)d_in[4];
    const float* ln_s = (const float*)d_in[5];
    const float* ln_b = (const float*)d_in[6];
    const float* Wp   = (const float*)d_in[7];
    const float* bp   = (const float*)d_in[8];
    const float* Wo   = (const float*)d_in[9];
    const float* bo   = (const float*)d_in[10];
    float* out = (float*)d_out;

    // workspace layout
    ushort* xb  = (ushort*)d_ws;                                   // 1024*2048*2 = 4,194,304 B
    ushort* wpt = (ushort*)((char*)d_ws + 4194304);                // 496*4096*2  = 4,063,232 B
    float*  dts = (float*)((char*)d_ws + 4194304 + 4063232);       // 1024*496*4  = 2,031,616 B

    k_cvt_x<<<2048, 256, 0, stream>>>(x, xb);
    k_cvt_wp<<<P_PAIRS, 256, 0, stream>>>(Wp, wpt);
    k_senet<<<B_SZ / 4, 512, 0, stream>>>(x, W1, b1, W2, b2, ln_s, ln_b, out);
    k_dots<<<P_PAIRS * 16, 256, 0, stream>>>(xb, wpt, x, bp, dts);
    k_bilinear<<<(B_SZ / 8) * 2, 256, 0, stream>>>(dts, Wo, bo, out);
}

// Round 2
// 90.500 us; speedup vs baseline: 2.3548x; 2.3548x over previous
//
#include <hip/hip_runtime.h>
#include <hip/hip_bf16.h>

#define F_FEAT 32
#define D_DIM 64
#define B_SZ 1024
#define EMB 2048
#define P_PAIRS 496
#define KPAD 512
#define OUT_N 512
#define OUT_STRIDE 2560
#define LN_EPS 1e-6f

typedef __attribute__((ext_vector_type(8))) short bf16x8;
typedef __attribute__((ext_vector_type(4))) float f32x4;

__device__ inline ushort f2bf(float f) {
    union { float f; unsigned u; } a; a.f = f;
    unsigned u = a.u;
    unsigned r = (u + 0x7FFFu + ((u >> 16) & 1u)) >> 16;   // RTNE
    return (ushort)r;
}

// ---------- convert x (fp32) -> bf16, 4 elems/thread ----------
__global__ void k_cvt_x(const float* __restrict__ x, ushort* __restrict__ xb) {
    int i = blockIdx.x * blockDim.x + threadIdx.x;
    int base = i * 4;
    float4 v = *reinterpret_cast<const float4*>(x + base);
    ushort4 o;
    o.x = f2bf(v.x); o.y = f2bf(v.y); o.z = f2bf(v.z); o.w = f2bf(v.w);
    *reinterpret_cast<ushort4*>(xb + base) = o;
}

// ---------- convert+transpose Wp[p][d][e] -> Wpt[p][e][d] bf16 ----------
__global__ void k_cvt_wp(const float* __restrict__ Wp, ushort* __restrict__ Wpt) {
    int p = blockIdx.x;
    const float* src = Wp + (size_t)p * 4096;
    ushort* dst = Wpt + (size_t)p * 4096;
    for (int idx = threadIdx.x; idx < 4096; idx += 256) {
        int d = idx >> 6, e = idx & 63;
        dst[e * 64 + d] = f2bf(src[d * 64 + e]);
    }
}

// ---------- convert+transpose Wo[k][n] fp32 -> Wot[n][k] bf16, K padded 496->512 ----------
__global__ __launch_bounds__(256) void k_cvt_wo(const float* __restrict__ Wo,
                                                ushort* __restrict__ Wot) {
    __shared__ float tile[64][65];
    int k0 = (blockIdx.x & 7) * 64;      // 8 k-tiles (incl pad)
    int n0 = (blockIdx.x >> 3) * 64;     // 8 n-tiles
    int t = threadIdx.x;
#pragma unroll
    for (int it = 0; it < 4; ++it) {
        int kr = it * 16 + (t >> 4);
        int nc = (t & 15) * 4;
        int k = k0 + kr;
        float4 v = {0.f, 0.f, 0.f, 0.f};
        if (k < P_PAIRS) v = *reinterpret_cast<const float4*>(Wo + (size_t)k * OUT_N + n0 + nc);
        tile[kr][nc] = v.x; tile[kr][nc + 1] = v.y; tile[kr][nc + 2] = v.z; tile[kr][nc + 3] = v.w;
    }
    __syncthreads();
#pragma unroll
    for (int it = 0; it < 4; ++it) {
        int nr = it * 16 + (t >> 4);
        int kc = (t & 15) * 4;
        ushort4 o;
        o.x = f2bf(tile[kc][nr]);     o.y = f2bf(tile[kc + 1][nr]);
        o.z = f2bf(tile[kc + 2][nr]); o.w = f2bf(tile[kc + 3][nr]);
        *reinterpret_cast<ushort4*>(Wot + (size_t)(n0 + nr) * KPAD + k0 + kc) = o;
    }
}

// ---------- SENet branch: squeeze -> MLP -> reweight -> LayerNorm ----------
__global__ __launch_bounds__(512) void k_senet(
        const float* __restrict__ x,
        const float* __restrict__ W1, const float* __restrict__ b1,
        const float* __restrict__ W2, const float* __restrict__ b2,
        const float* __restrict__ ln_s, const float* __restrict__ ln_b,
        float* __restrict__ out) {
    __shared__ float xs[4][EMB];
    __shared__ float zs[4][128];
    __shared__ float a1s[4][32];
    __shared__ float red[2][4][8];
    int t = threadIdx.x;
    int b0 = blockIdx.x * 4;

    for (int r = 0; r < 4; ++r) {
        const float4* src = reinterpret_cast<const float4*>(x + (size_t)(b0 + r) * EMB);
        float4* dstv = reinterpret_cast<float4*>(&xs[r][0]);
        dstv[t] = src[t];
    }
    __syncthreads();

    if (t < 256) {
        int r = t >> 6, f = (t >> 1) & 31, gg = t & 1;
        const float* base = &xs[r][f * 64 + gg * 32];
        float mx = -INFINITY, sm = 0.f;
        for (int q = 0; q < 32; ++q) {
            float v = base[(q + t) & 31];
            mx = fmaxf(mx, v); sm += v;
        }
        zs[r][f * 4 + gg]     = mx;
        zs[r][f * 4 + 2 + gg] = sm * (1.f / 32.f);
    }
    __syncthreads();

    if (t < 128) {
        int r = t >> 5, c = t & 31;
        float acc = b1[c];
        for (int k = 0; k < 128; ++k) acc += zs[r][k] * W1[k * 32 + c];
        a1s[r][c] = fmaxf(acc, 0.f);
    }
    __syncthreads();

    float acc[4][4];
#pragma unroll
    for (int r = 0; r < 4; ++r)
#pragma unroll
        for (int u = 0; u < 4; ++u) acc[r][u] = 0.f;

    for (int k = 0; k < 32; ++k) {
        float a0 = a1s[0][k], a1v = a1s[1][k], a2 = a1s[2][k], a3 = a1s[3][k];
#pragma unroll
        for (int u = 0; u < 4; ++u) {
            float wv = W2[k * EMB + t + 512 * u];
            acc[0][u] += a0 * wv; acc[1][u] += a1v * wv;
            acc[2][u] += a2 * wv; acc[3][u] += a3 * wv;
        }
    }
    float ssum[4], ssq[4];
#pragma unroll
    for (int r = 0; r < 4; ++r) { ssum[r] = 0.f; ssq[r] = 0.f; }
#pragma unroll
    for (int r = 0; r < 4; ++r) {
#pragma unroll
        for (int u = 0; u < 4; ++u) {
            int e = t + 512 * u;
            float w = acc[r][u] + b2[e];
            float s = xs[r][e] * (w + 1.0f);
            xs[r][e] = s;
            ssum[r] += s; ssq[r] += s * s;
        }
    }
    int lane = t & 63, w = t >> 6;
#pragma unroll
    for (int r = 0; r < 4; ++r) {
        float a = ssum[r], q = ssq[r];
        for (int off = 32; off; off >>= 1) { a += __shfl_down(a, off); q += __shfl_down(q, off); }
        if (lane == 0) { red[0][r][w] = a; red[1][r][w] = q; }
    }
    __syncthreads();
    float mu[4], rs[4];
#pragma unroll
    for (int r = 0; r < 4; ++r) {
        float a = 0.f, q = 0.f;
#pragma unroll
        for (int i = 0; i < 8; ++i) { a += red[0][r][i]; q += red[1][r][i]; }
        mu[r] = a * (1.f / 2048.f);
        float var = q * (1.f / 2048.f) - mu[r] * mu[r];
        rs[r] = rsqrtf(var + LN_EPS);
    }
#pragma unroll
    for (int r = 0; r < 4; ++r) {
#pragma unroll
        for (int u = 0; u < 4; ++u) {
            int e = t + 512 * u;
            float s = xs[r][e];
            out[(size_t)(b0 + r) * OUT_STRIDE + e] = (s - mu[r]) * rs[r] * ln_s[e] + ln_b[e];
        }
    }
}

// ---------- pair bilinear: dots[b,p] = (x_i^T Wp_p + bp_p) . x_j  via MFMA ----------
// writes bf16 dots into db[b][KPAD] (pad columns pre-zeroed by memset)
__global__ __launch_bounds__(256) void k_dots(
        const ushort* __restrict__ xb, const ushort* __restrict__ Wpt,
        const float* __restrict__ x, const float* __restrict__ bp,
        ushort* __restrict__ db) {
    int bt = blockIdx.x & 15;
    int p  = blockIdx.x >> 4;
    int i = 0, rem = p;
    while (rem >= F_FEAT - 1 - i) { rem -= F_FEAT - 1 - i; ++i; }
    int j = i + 1 + rem;

    int wave = threadIdx.x >> 6, lane = threadIdx.x & 63;
    int b0 = bt * 64 + wave * 16;
    int row = lane & 15, kg = lane >> 4;

    bf16x8 afr[2];
#pragma unroll
    for (int ks = 0; ks < 2; ++ks)
        afr[ks] = *reinterpret_cast<const bf16x8*>(
            xb + (size_t)(b0 + row) * EMB + i * 64 + ks * 32 + kg * 8);

    bf16x8 bfr[4][2];
#pragma unroll
    for (int nt = 0; nt < 4; ++nt)
#pragma unroll
        for (int ks = 0; ks < 2; ++ks)
            bfr[nt][ks] = *reinterpret_cast<const bf16x8*>(
                Wpt + (size_t)p * 4096 + (nt * 16 + row) * 64 + ks * 32 + kg * 8);

    f32x4 acc[4];
#pragma unroll
    for (int nt = 0; nt < 4; ++nt) {
        f32x4 z = {0.f, 0.f, 0.f, 0.f};
        acc[nt] = z;
    }
#pragma unroll
    for (int nt = 0; nt < 4; ++nt) {
        acc[nt] = __builtin_amdgcn_mfma_f32_16x16x32_bf16(afr[0], bfr[nt][0], acc[nt], 0, 0, 0);
        acc[nt] = __builtin_amdgcn_mfma_f32_16x16x32_bf16(afr[1], bfr[nt][1], acc[nt], 0, 0, 0);
    }

    int col = row;
    float part[4] = {0.f, 0.f, 0.f, 0.f};
#pragma unroll
    for (int nt = 0; nt < 4; ++nt) {
        float bpv = bp[p * 64 + nt * 16 + col];
#pragma unroll
        for (int r = 0; r < 4; ++r) {
            int brow = b0 + kg * 4 + r;
            float xjv = x[(size_t)brow * EMB + j * 64 + nt * 16 + col];
            part[r] += (acc[nt][r] + bpv) * xjv;
        }
    }
#pragma unroll
    for (int r = 0; r < 4; ++r) {
        float v = part[r];
        v += __shfl_xor(v, 1); v += __shfl_xor(v, 2);
        v += __shfl_xor(v, 4); v += __shfl_xor(v, 8);
        part[r] = v;
    }
    if (col == 0) {
#pragma unroll
        for (int r = 0; r < 4; ++r)
            db[(size_t)(b0 + kg * 4 + r) * KPAD + p] = f2bf(part[r]);
    }
}

// ---------- bilinear head via MFMA: out[:,2048:] = db @ Wot^T + bo ----------
__global__ __launch_bounds__(256) void k_bilin2(
        const ushort* __restrict__ db, const ushort* __restrict__ Wot,
        const float* __restrict__ bo, float* __restrict__ out) {
    int mt  = blockIdx.x >> 4;        // 16 m-tiles of 64
    int nt0 = blockIdx.x & 15;        // 16 n-tiles of 32
    int wave = threadIdx.x >> 6, lane = threadIdx.x & 63;
    int row = lane & 15, kg = lane >> 4;
    int m0 = mt * 64 + wave * 16;
    int n0 = nt0 * 32;

    f32x4 acc0 = {0.f, 0.f, 0.f, 0.f};
    f32x4 acc1 = {0.f, 0.f, 0.f, 0.f};
    const ushort* arow  = db  + (size_t)(m0 + row) * KPAD + kg * 8;
    const ushort* brow0 = Wot + (size_t)(n0 + row) * KPAD + kg * 8;
    const ushort* brow1 = brow0 + 16 * KPAD;
#pragma unroll
    for (int ks = 0; ks < 16; ++ks) {
        bf16x8 a  = *reinterpret_cast<const bf16x8*>(arow  + ks * 32);
        bf16x8 b0 = *reinterpret_cast<const bf16x8*>(brow0 + ks * 32);
        bf16x8 b1 = *reinterpret_cast<const bf16x8*>(brow1 + ks * 32);
        acc0 = __builtin_amdgcn_mfma_f32_16x16x32_bf16(a, b0, acc0, 0, 0, 0);
        acc1 = __builtin_amdgcn_mfma_f32_16x16x32_bf16(a, b1, acc1, 0, 0, 0);
    }
    int col = row;
    float bo0 = bo[n0 + col], bo1 = bo[n0 + 16 + col];
#pragma unroll
    for (int r = 0; r < 4; ++r) {
        size_t orow = (size_t)(m0 + kg * 4 + r) * OUT_STRIDE + 2048 + n0;
        out[orow + col]      = acc0[r] + bo0;
        out[orow + 16 + col] = acc1[r] + bo1;
    }
}

extern "C" void kernel_launch(void* const* d_in, const int* in_sizes, int n_in,
                              void* d_out, int out_size, void* d_ws, size_t ws_size,
                              hipStream_t stream) {
    const float* x    = (const float*)d_in[0];
    const float* W1   = (const float*)d_in[1];
    const float* b1   = (const float*)d_in[2];
    const float* W2   = (const float*)d_in[3];
    const float* b2   = (const float*)d_in[4];
    const float* ln_s = (const float*)d_in[5];
    const float* ln_b = (const float*)d_in[6];
    const float* Wp   = (const float*)d_in[7];
    const float* bp   = (const float*)d_in[8];
    const float* Wo   = (const float*)d_in[9];
    const float* bo   = (const float*)d_in[10];
    float* out = (float*)d_out;

    // workspace layout
    ushort* xb   = (ushort*)d_ws;                                    // 1024*2048*2 = 4,194,304 B
    ushort* wpt  = (ushort*)((char*)d_ws + 4194304);                 // 496*4096*2  = 4,063,232 B
    ushort* db   = (ushort*)((char*)d_ws + 4194304 + 4063232);       // 1024*512*2  = 1,048,576 B
    ushort* wot  = (ushort*)((char*)d_ws + 4194304 + 4063232 + 1048576); // 512*512*2 = 524,288 B

    hipMemsetAsync(db, 0, (size_t)B_SZ * KPAD * 2, stream);          // zero K-pad cols
    k_cvt_x<<<2048, 256, 0, stream>>>(x, xb);
    k_cvt_wp<<<P_PAIRS, 256, 0, stream>>>(Wp, wpt);
    k_cvt_wo<<<64, 256, 0, stream>>>(Wo, wot);
    k_senet<<<B_SZ / 4, 512, 0, stream>>>(x, W1, b1, W2, b2, ln_s, ln_b, out);
    k_dots<<<P_PAIRS * 16, 256, 0, stream>>>(xb, wpt, x, bp, db);
    k_bilin2<<<256, 256, 0, stream>>>(db, wot, bo, out);
}

// Round 3
// 62.699 us; speedup vs baseline: 3.3989x; 1.4434x over previous
//
#include <hip/hip_runtime.h>
#include <hip/hip_bf16.h>

#define F_FEAT 32
#define D_DIM 64
#define B_SZ 1024
#define EMB 2048
#define P_PAIRS 496
#define KPAD 512
#define OUT_N 512
#define OUT_STRIDE 2560
#define LN_EPS 1e-6f

typedef __attribute__((ext_vector_type(8))) short bf16x8;
typedef __attribute__((ext_vector_type(4))) float f32x4;

__device__ inline ushort f2bf(float f) {
    union { float f; unsigned u; } a; a.f = f;
    unsigned u = a.u;
    unsigned r = (u + 0x7FFFu + ((u >> 16) & 1u)) >> 16;   // RTNE
    return (ushort)r;
}

// ---------- fused prep: cvt x->bf16 | cvt+transpose Wp | cvt+transpose Wo | zero db pad ----
// blocks [0,1024)          : x fp32 -> xb bf16, 8 elems/thread
// blocks [1024,1520)       : Wp[p][d][e] -> Wpt[p][e][d] bf16 (LDS transpose)
// blocks [1520,1584)       : Wo[k][n] -> Wot[n][k] bf16, k padded to 512
// blocks [1584,1592)       : zero db[:, 496:512]
__global__ __launch_bounds__(256) void k_prep(
        const float* __restrict__ x, ushort* __restrict__ xb,
        const float* __restrict__ Wp, ushort* __restrict__ Wpt,
        const float* __restrict__ Wo, ushort* __restrict__ Wot,
        ushort* __restrict__ db) {
    __shared__ float tile[64][65];
    int t = threadIdx.x;
    int blk = blockIdx.x;

    if (blk < 1024) {                       // ---- cvt x ----
        size_t base = ((size_t)blk * 256 + t) * 8;
        float4 v0 = *reinterpret_cast<const float4*>(x + base);
        float4 v1 = *reinterpret_cast<const float4*>(x + base + 4);
        bf16x8 o;
        o[0] = f2bf(v0.x); o[1] = f2bf(v0.y); o[2] = f2bf(v0.z); o[3] = f2bf(v0.w);
        o[4] = f2bf(v1.x); o[5] = f2bf(v1.y); o[6] = f2bf(v1.z); o[7] = f2bf(v1.w);
        *reinterpret_cast<bf16x8*>(xb + base) = o;
    } else if (blk < 1520) {                // ---- cvt+transpose Wp ----
        int p = blk - 1024;
        const float* src = Wp + (size_t)p * 4096;
        ushort* dst = Wpt + (size_t)p * 4096;
#pragma unroll
        for (int it = 0; it < 4; ++it) {
            int d = it * 16 + (t >> 4);
            int e4 = (t & 15) * 4;
            float4 v = *reinterpret_cast<const float4*>(src + d * 64 + e4);
            tile[d][e4] = v.x; tile[d][e4 + 1] = v.y; tile[d][e4 + 2] = v.z; tile[d][e4 + 3] = v.w;
        }
        __syncthreads();
#pragma unroll
        for (int it = 0; it < 4; ++it) {
            int e = it * 16 + (t >> 4);
            int d4 = (t & 15) * 4;
            ushort4 o;
            o.x = f2bf(tile[d4][e]);     o.y = f2bf(tile[d4 + 1][e]);
            o.z = f2bf(tile[d4 + 2][e]); o.w = f2bf(tile[d4 + 3][e]);
            *reinterpret_cast<ushort4*>(dst + e * 64 + d4) = o;
        }
    } else if (blk < 1584) {                // ---- cvt+transpose Wo ----
        int bidx = blk - 1520;
        int k0 = (bidx & 7) * 64;
        int n0 = (bidx >> 3) * 64;
#pragma unroll
        for (int it = 0; it < 4; ++it) {
            int kr = it * 16 + (t >> 4);
            int nc = (t & 15) * 4;
            int k = k0 + kr;
            float4 v = {0.f, 0.f, 0.f, 0.f};
            if (k < P_PAIRS) v = *reinterpret_cast<const float4*>(Wo + (size_t)k * OUT_N + n0 + nc);
            tile[kr][nc] = v.x; tile[kr][nc + 1] = v.y; tile[kr][nc + 2] = v.z; tile[kr][nc + 3] = v.w;
        }
        __syncthreads();
#pragma unroll
        for (int it = 0; it < 4; ++it) {
            int nr = it * 16 + (t >> 4);
            int kc = (t & 15) * 4;
            ushort4 o;
            o.x = f2bf(tile[kc][nr]);     o.y = f2bf(tile[kc + 1][nr]);
            o.z = f2bf(tile[kc + 2][nr]); o.w = f2bf(tile[kc + 3][nr]);
            *reinterpret_cast<ushort4*>(Wot + (size_t)(n0 + nr) * KPAD + k0 + kc) = o;
        }
    } else {                                // ---- zero db pad cols ----
        int tid = (blk - 1584) * 256 + t;
        if (tid < B_SZ) {
            bf16x8 z = {0, 0, 0, 0, 0, 0, 0, 0};
            ushort* dstp = db + (size_t)tid * KPAD + P_PAIRS;
            *reinterpret_cast<bf16x8*>(dstp) = z;
            *reinterpret_cast<bf16x8*>(dstp + 8) = z;
        }
    }
}

// ---------- SENet branch: squeeze -> MLP -> reweight -> LayerNorm ----------
__global__ __launch_bounds__(512) void k_senet(
        const float* __restrict__ x,
        const float* __restrict__ W1, const float* __restrict__ b1,
        const float* __restrict__ W2, const float* __restrict__ b2,
        const float* __restrict__ ln_s, const float* __restrict__ ln_b,
        float* __restrict__ out) {
    __shared__ float xs[4][EMB];
    __shared__ float zs[4][128];
    __shared__ float a1s[4][32];
    __shared__ float red[2][4][8];
    int t = threadIdx.x;
    int b0 = blockIdx.x * 4;

    for (int r = 0; r < 4; ++r) {
        const float4* src = reinterpret_cast<const float4*>(x + (size_t)(b0 + r) * EMB);
        float4* dstv = reinterpret_cast<float4*>(&xs[r][0]);
        dstv[t] = src[t];
    }
    __syncthreads();

    if (t < 256) {
        int r = t >> 6, f = (t >> 1) & 31, gg = t & 1;
        const float* base = &xs[r][f * 64 + gg * 32];
        float mx = -INFINITY, sm = 0.f;
        for (int q = 0; q < 32; ++q) {
            float v = base[(q + t) & 31];
            mx = fmaxf(mx, v); sm += v;
        }
        zs[r][f * 4 + gg]     = mx;
        zs[r][f * 4 + 2 + gg] = sm * (1.f / 32.f);
    }
    __syncthreads();

    if (t < 128) {
        int r = t >> 5, c = t & 31;
        float acc = b1[c];
        for (int k = 0; k < 128; ++k) acc += zs[r][k] * W1[k * 32 + c];
        a1s[r][c] = fmaxf(acc, 0.f);
    }
    __syncthreads();

    float acc[4][4];
#pragma unroll
    for (int r = 0; r < 4; ++r)
#pragma unroll
        for (int u = 0; u < 4; ++u) acc[r][u] = 0.f;

    for (int k = 0; k < 32; ++k) {
        float a0 = a1s[0][k], a1v = a1s[1][k], a2 = a1s[2][k], a3 = a1s[3][k];
#pragma unroll
        for (int u = 0; u < 4; ++u) {
            float wv = W2[k * EMB + t + 512 * u];
            acc[0][u] += a0 * wv; acc[1][u] += a1v * wv;
            acc[2][u] += a2 * wv; acc[3][u] += a3 * wv;
        }
    }
    float ssum[4], ssq[4];
#pragma unroll
    for (int r = 0; r < 4; ++r) { ssum[r] = 0.f; ssq[r] = 0.f; }
#pragma unroll
    for (int r = 0; r < 4; ++r) {
#pragma unroll
        for (int u = 0; u < 4; ++u) {
            int e = t + 512 * u;
            float w = acc[r][u] + b2[e];
            float s = xs[r][e] * (w + 1.0f);
            xs[r][e] = s;
            ssum[r] += s; ssq[r] += s * s;
        }
    }
    int lane = t & 63, w = t >> 6;
#pragma unroll
    for (int r = 0; r < 4; ++r) {
        float a = ssum[r], q = ssq[r];
        for (int off = 32; off; off >>= 1) { a += __shfl_down(a, off); q += __shfl_down(q, off); }
        if (lane == 0) { red[0][r][w] = a; red[1][r][w] = q; }
    }
    __syncthreads();
    float mu[4], rs[4];
#pragma unroll
    for (int r = 0; r < 4; ++r) {
        float a = 0.f, q = 0.f;
#pragma unroll
        for (int i = 0; i < 8; ++i) { a += red[0][r][i]; q += red[1][r][i]; }
        mu[r] = a * (1.f / 2048.f);
        float var = q * (1.f / 2048.f) - mu[r] * mu[r];
        rs[r] = rsqrtf(var + LN_EPS);
    }
#pragma unroll
    for (int r = 0; r < 4; ++r) {
#pragma unroll
        for (int u = 0; u < 4; ++u) {
            int e = t + 512 * u;
            float s = xs[r][e];
            out[(size_t)(b0 + r) * OUT_STRIDE + e] = (s - mu[r]) * rs[r] * ln_s[e] + ln_b[e];
        }
    }
}

// ---------- pair bilinear via transposed MFMA: lane-local e-reduction ----------
// grid: 496 pairs x 4 quarter-batches. Per block: Wp frags register-resident,
// 4 waves x 4 tiles of 16 batch rows. dots -> db bf16.
__global__ __launch_bounds__(256) void k_dots(
        const ushort* __restrict__ xb, const ushort* __restrict__ Wpt,
        const float* __restrict__ x, const float* __restrict__ bp,
        ushort* __restrict__ db) {
    int p = blockIdx.x >> 2;
    int q = blockIdx.x & 3;
    int i = 0, rem = p;
    while (rem >= F_FEAT - 1 - i) { rem -= F_FEAT - 1 - i; ++i; }
    int j = i + 1 + rem;

    int wave = threadIdx.x >> 6, lane = threadIdx.x & 63;
    int row = lane & 15, kg = lane >> 4;   // row: e-row (A) / batch col (B,C)

    // A frags: Wp^T tile rows = e, k = d (loaded once, register-resident)
    bf16x8 wfr[4][2];
#pragma unroll
    for (int nt = 0; nt < 4; ++nt)
#pragma unroll
        for (int ks = 0; ks < 2; ++ks)
            wfr[nt][ks] = *reinterpret_cast<const bf16x8*>(
                Wpt + (size_t)p * 4096 + (nt * 16 + row) * 64 + ks * 32 + kg * 8);

    // bias bp[p][e] for this lane's e-indices: e = nt*16 + kg*4 + r
    f32x4 bb[4];
#pragma unroll
    for (int nt = 0; nt < 4; ++nt)
        bb[nt] = *reinterpret_cast<const f32x4*>(bp + p * 64 + nt * 16 + kg * 4);

#pragma unroll
    for (int it = 0; it < 4; ++it) {
        int b0 = q * 256 + (wave * 4 + it) * 16;

        // B frags: Xi^T, cols = batch (row), k = d
        bf16x8 xifr[2];
#pragma unroll
        for (int ks = 0; ks < 2; ++ks)
            xifr[ks] = *reinterpret_cast<const bf16x8*>(
                xb + (size_t)(b0 + row) * EMB + i * 64 + ks * 32 + kg * 8);

        // xj values for this lane: batch col = b0+row, e = nt*16+kg*4+{0..3}
        f32x4 xjv[4];
#pragma unroll
        for (int nt = 0; nt < 4; ++nt)
            xjv[nt] = *reinterpret_cast<const f32x4*>(
                x + (size_t)(b0 + row) * EMB + j * 64 + nt * 16 + kg * 4);

        f32x4 acc[4];
#pragma unroll
        for (int nt = 0; nt < 4; ++nt) {
            f32x4 z = {0.f, 0.f, 0.f, 0.f};
            acc[nt] = z;
            acc[nt] = __builtin_amdgcn_mfma_f32_16x16x32_bf16(wfr[nt][0], xifr[0], acc[nt], 0, 0, 0);
            acc[nt] = __builtin_amdgcn_mfma_f32_16x16x32_bf16(wfr[nt][1], xifr[1], acc[nt], 0, 0, 0);
        }

        // lane-local partial dot over its 16 e-values, then reduce over kg
        float v = 0.f;
#pragma unroll
        for (int nt = 0; nt < 4; ++nt)
#pragma unroll
            for (int r = 0; r < 4; ++r)
                v += (acc[nt][r] + bb[nt][r]) * xjv[nt][r];
        v += __shfl_xor(v, 16);
        v += __shfl_xor(v, 32);
        if (lane < 16)
            db[(size_t)(b0 + lane) * KPAD + p] = f2bf(v);
    }
}

// ---------- bilinear head via MFMA: out[:,2048:] = db @ Wot^T + bo ----------
__global__ __launch_bounds__(256) void k_bilin2(
        const ushort* __restrict__ db, const ushort* __restrict__ Wot,
        const float* __restrict__ bo, float* __restrict__ out) {
    int mt  = blockIdx.x >> 4;        // 16 m-tiles of 64
    int nt0 = blockIdx.x & 15;        // 16 n-tiles of 32
    int wave = threadIdx.x >> 6, lane = threadIdx.x & 63;
    int row = lane & 15, kg = lane >> 4;
    int m0 = mt * 64 + wave * 16;
    int n0 = nt0 * 32;

    f32x4 acc0 = {0.f, 0.f, 0.f, 0.f};
    f32x4 acc1 = {0.f, 0.f, 0.f, 0.f};
    const ushort* arow  = db  + (size_t)(m0 + row) * KPAD + kg * 8;
    const ushort* brow0 = Wot + (size_t)(n0 + row) * KPAD + kg * 8;
    const ushort* brow1 = brow0 + 16 * KPAD;
#pragma unroll
    for (int ks = 0; ks < 16; ++ks) {
        bf16x8 a  = *reinterpret_cast<const bf16x8*>(arow  + ks * 32);
        bf16x8 b0 = *reinterpret_cast<const bf16x8*>(brow0 + ks * 32);
        bf16x8 b1 = *reinterpret_cast<const bf16x8*>(brow1 + ks * 32);
        acc0 = __builtin_amdgcn_mfma_f32_16x16x32_bf16(a, b0, acc0, 0, 0, 0);
        acc1 = __builtin_amdgcn_mfma_f32_16x16x32_bf16(a, b1, acc1, 0, 0, 0);
    }
    int col = row;
    float bo0 = bo[n0 + col], bo1 = bo[n0 + 16 + col];
#pragma unroll
    for (int r = 0; r < 4; ++r) {
        size_t orow = (size_t)(m0 + kg * 4 + r) * OUT_STRIDE + 2048 + n0;
        out[orow + col]      = acc0[r] + bo0;
        out[orow + 16 + col] = acc1[r] + bo1;
    }
}

extern "C" void kernel_launch(void* const* d_in, const int* in_sizes, int n_in,
                              void* d_out, int out_size, void* d_ws, size_t ws_size,
                              hipStream_t stream) {
    const float* x    = (const float*)d_in[0];
    const float* W1   = (const float*)d_in[1];
    const float* b1   = (const float*)d_in[2];
    const float* W2   = (const float*)d_in[3];
    const float* b2   = (const float*)d_in[4];
    const float* ln_s = (const float*)d_in[5];
    const float* ln_b = (const float*)d_in[6];
    const float* Wp   = (const float*)d_in[7];
    const float* bp   = (const float*)d_in[8];
    const float* Wo   = (const float*)d_in[9];
    const float* bo   = (const float*)d_in[10];
    float* out = (float*)d_out;

    // workspace layout
    ushort* xb   = (ushort*)d_ws;                                        // 4,194,304 B
    ushort* wpt  = (ushort*)((char*)d_ws + 4194304);                     // 4,063,232 B
    ushort* db   = (ushort*)((char*)d_ws + 4194304 + 4063232);           // 1,048,576 B
    ushort* wot  = (ushort*)((char*)d_ws + 4194304 + 4063232 + 1048576); //   524,288 B

    k_prep<<<1592, 256, 0, stream>>>(x, xb, Wp, wpt, Wo, wot, db);
    k_senet<<<B_SZ / 4, 512, 0, stream>>>(x, W1, b1, W2, b2, ln_s, ln_b, out);
    k_dots<<<P_PAIRS * 4, 256, 0, stream>>>(xb, wpt, x, bp, db);
    k_bilin2<<<256, 256, 0, stream>>>(db, wot, bo, out);
}

// Round 4
// 59.175 us; speedup vs baseline: 3.6013x; 1.0595x over previous
//
#include <hip/hip_runtime.h>
#include <hip/hip_bf16.h>

#define F_FEAT 32
#define D_DIM 64
#define B_SZ 1024
#define EMB 2048
#define P_PAIRS 496
#define KPAD 512
#define OUT_N 512
#define OUT_STRIDE 2560
#define LN_EPS 1e-6f

typedef __attribute__((ext_vector_type(8))) short bf16x8;
typedef __attribute__((ext_vector_type(4))) float f32x4;

__device__ inline ushort f2bf(float f) {
    union { float f; unsigned u; } a; a.f = f;
    unsigned u = a.u;
    unsigned r = (u + 0x7FFFu + ((u >> 16) & 1u)) >> 16;   // RTNE
    return (ushort)r;
}
__device__ inline float bf2f(ushort u) {
    union { unsigned u; float f; } a; a.u = ((unsigned)u) << 16;
    return a.f;
}

// ---------- prep: cvt+transpose Wp | cvt+transpose Wo | zero db pad ----------
// blocks [0,496)     : Wp[p][d][e] -> Wpt[p][e][d] bf16 (LDS transpose)
// blocks [496,560)   : Wo[k][n] -> Wot[n][k] bf16, k padded to 512
// blocks [560,568)   : zero db[:, 496:512]
__global__ __launch_bounds__(256) void k_prep(
        const float* __restrict__ Wp, ushort* __restrict__ Wpt,
        const float* __restrict__ Wo, ushort* __restrict__ Wot,
        ushort* __restrict__ db) {
    __shared__ float tile[64][65];
    int t = threadIdx.x;
    int blk = blockIdx.x;

    if (blk < 496) {                        // ---- cvt+transpose Wp ----
        int p = blk;
        const float* src = Wp + (size_t)p * 4096;
        ushort* dst = Wpt + (size_t)p * 4096;
#pragma unroll
        for (int it = 0; it < 4; ++it) {
            int d = it * 16 + (t >> 4);
            int e4 = (t & 15) * 4;
            float4 v = *reinterpret_cast<const float4*>(src + d * 64 + e4);
            tile[d][e4] = v.x; tile[d][e4 + 1] = v.y; tile[d][e4 + 2] = v.z; tile[d][e4 + 3] = v.w;
        }
        __syncthreads();
#pragma unroll
        for (int it = 0; it < 4; ++it) {
            int e = it * 16 + (t >> 4);
            int d4 = (t & 15) * 4;
            ushort4 o;
            o.x = f2bf(tile[d4][e]);     o.y = f2bf(tile[d4 + 1][e]);
            o.z = f2bf(tile[d4 + 2][e]); o.w = f2bf(tile[d4 + 3][e]);
            *reinterpret_cast<ushort4*>(dst + e * 64 + d4) = o;
        }
    } else if (blk < 560) {                 // ---- cvt+transpose Wo ----
        int bidx = blk - 496;
        int k0 = (bidx & 7) * 64;
        int n0 = (bidx >> 3) * 64;
#pragma unroll
        for (int it = 0; it < 4; ++it) {
            int kr = it * 16 + (t >> 4);
            int nc = (t & 15) * 4;
            int k = k0 + kr;
            float4 v = {0.f, 0.f, 0.f, 0.f};
            if (k < P_PAIRS) v = *reinterpret_cast<const float4*>(Wo + (size_t)k * OUT_N + n0 + nc);
            tile[kr][nc] = v.x; tile[kr][nc + 1] = v.y; tile[kr][nc + 2] = v.z; tile[kr][nc + 3] = v.w;
        }
        __syncthreads();
#pragma unroll
        for (int it = 0; it < 4; ++it) {
            int nr = it * 16 + (t >> 4);
            int kc = (t & 15) * 4;
            ushort4 o;
            o.x = f2bf(tile[kc][nr]);     o.y = f2bf(tile[kc + 1][nr]);
            o.z = f2bf(tile[kc + 2][nr]); o.w = f2bf(tile[kc + 3][nr]);
            *reinterpret_cast<ushort4*>(Wot + (size_t)(n0 + nr) * KPAD + k0 + kc) = o;
        }
    } else {                                // ---- zero db pad cols ----
        int tid = (blk - 560) * 256 + t;
        if (tid < B_SZ) {
            bf16x8 z = {0, 0, 0, 0, 0, 0, 0, 0};
            ushort* dstp = db + (size_t)tid * KPAD + P_PAIRS;
            *reinterpret_cast<bf16x8*>(dstp) = z;
            *reinterpret_cast<bf16x8*>(dstp + 8) = z;
        }
    }
}

// ---------- SENet branch (also emits xb = bf16(x) as side product) ----------
__global__ __launch_bounds__(512) void k_senet(
        const float* __restrict__ x, ushort* __restrict__ xb,
        const float* __restrict__ W1, const float* __restrict__ b1,
        const float* __restrict__ W2, const float* __restrict__ b2,
        const float* __restrict__ ln_s, const float* __restrict__ ln_b,
        float* __restrict__ out) {
    __shared__ float xs[4][EMB];
    __shared__ float zs[4][128];
    __shared__ float a1s[4][32];
    __shared__ float red[2][4][8];
    int t = threadIdx.x;
    int b0 = blockIdx.x * 4;

    for (int r = 0; r < 4; ++r) {
        const float4* src = reinterpret_cast<const float4*>(x + (size_t)(b0 + r) * EMB);
        float4 v = src[t];
        reinterpret_cast<float4*>(&xs[r][0])[t] = v;
        ushort4 o;
        o.x = f2bf(v.x); o.y = f2bf(v.y); o.z = f2bf(v.z); o.w = f2bf(v.w);
        *reinterpret_cast<ushort4*>(xb + (size_t)(b0 + r) * EMB + t * 4) = o;
    }
    __syncthreads();

    if (t < 256) {
        int r = t >> 6, f = (t >> 1) & 31, gg = t & 1;
        const float* base = &xs[r][f * 64 + gg * 32];
        float mx = -INFINITY, sm = 0.f;
        for (int q = 0; q < 32; ++q) {
            float v = base[(q + t) & 31];
            mx = fmaxf(mx, v); sm += v;
        }
        zs[r][f * 4 + gg]     = mx;
        zs[r][f * 4 + 2 + gg] = sm * (1.f / 32.f);
    }
    __syncthreads();

    if (t < 128) {
        int r = t >> 5, c = t & 31;
        float acc = b1[c];
        for (int k = 0; k < 128; ++k) acc += zs[r][k] * W1[k * 32 + c];
        a1s[r][c] = fmaxf(acc, 0.f);
    }
    __syncthreads();

    float acc[4][4];
#pragma unroll
    for (int r = 0; r < 4; ++r)
#pragma unroll
        for (int u = 0; u < 4; ++u) acc[r][u] = 0.f;

    for (int k = 0; k < 32; ++k) {
        float a0 = a1s[0][k], a1v = a1s[1][k], a2 = a1s[2][k], a3 = a1s[3][k];
#pragma unroll
        for (int u = 0; u < 4; ++u) {
            float wv = W2[k * EMB + t + 512 * u];
            acc[0][u] += a0 * wv; acc[1][u] += a1v * wv;
            acc[2][u] += a2 * wv; acc[3][u] += a3 * wv;
        }
    }
    float ssum[4], ssq[4];
#pragma unroll
    for (int r = 0; r < 4; ++r) { ssum[r] = 0.f; ssq[r] = 0.f; }
#pragma unroll
    for (int r = 0; r < 4; ++r) {
#pragma unroll
        for (int u = 0; u < 4; ++u) {
            int e = t + 512 * u;
            float w = acc[r][u] + b2[e];
            float s = xs[r][e] * (w + 1.0f);
            xs[r][e] = s;
            ssum[r] += s; ssq[r] += s * s;
        }
    }
    int lane = t & 63, w = t >> 6;
#pragma unroll
    for (int r = 0; r < 4; ++r) {
        float a = ssum[r], q = ssq[r];
        for (int off = 32; off; off >>= 1) { a += __shfl_down(a, off); q += __shfl_down(q, off); }
        if (lane == 0) { red[0][r][w] = a; red[1][r][w] = q; }
    }
    __syncthreads();
    float mu[4], rs[4];
#pragma unroll
    for (int r = 0; r < 4; ++r) {
        float a = 0.f, q = 0.f;
#pragma unroll
        for (int i = 0; i < 8; ++i) { a += red[0][r][i]; q += red[1][r][i]; }
        mu[r] = a * (1.f / 2048.f);
        float var = q * (1.f / 2048.f) - mu[r] * mu[r];
        rs[r] = rsqrtf(var + LN_EPS);
    }
#pragma unroll
    for (int r = 0; r < 4; ++r) {
#pragma unroll
        for (int u = 0; u < 4; ++u) {
            int e = t + 512 * u;
            float s = xs[r][e];
            out[(size_t)(b0 + r) * OUT_STRIDE + e] = (s - mu[r]) * rs[r] * ln_s[e] + ln_b[e];
        }
    }
}

// ---------- pair bilinear via transposed MFMA: lane-local e-reduction ----------
// grid: 496 pairs x 2 half-batches. 4 waves x 8 tiles of 16 batch rows.
// Wp frags register-resident; xi and xj both read as bf16 from xb.
__global__ __launch_bounds__(256) void k_dots(
        const ushort* __restrict__ xb, const ushort* __restrict__ Wpt,
        const float* __restrict__ bp, ushort* __restrict__ db) {
    int p = blockIdx.x >> 1;
    int h = blockIdx.x & 1;
    int i = 0, rem = p;
    while (rem >= F_FEAT - 1 - i) { rem -= F_FEAT - 1 - i; ++i; }
    int j = i + 1 + rem;

    int wave = threadIdx.x >> 6, lane = threadIdx.x & 63;
    int row = lane & 15, kg = lane >> 4;   // row: e-row (A) / batch col (B,C)

    // A frags: Wp^T tile rows = e, k = d (loaded once, register-resident)
    bf16x8 wfr[4][2];
#pragma unroll
    for (int nt = 0; nt < 4; ++nt)
#pragma unroll
        for (int ks = 0; ks < 2; ++ks)
            wfr[nt][ks] = *reinterpret_cast<const bf16x8*>(
                Wpt + (size_t)p * 4096 + (nt * 16 + row) * 64 + ks * 32 + kg * 8);

    // bias bp[p][e] for this lane's e-indices: e = nt*16 + kg*4 + r
    f32x4 bb[4];
#pragma unroll
    for (int nt = 0; nt < 4; ++nt)
        bb[nt] = *reinterpret_cast<const f32x4*>(bp + p * 64 + nt * 16 + kg * 4);

#pragma unroll
    for (int it = 0; it < 8; ++it) {
        int b0 = h * 512 + (wave * 8 + it) * 16;

        // B frags: Xi^T, cols = batch (row), k = d
        bf16x8 xifr[2];
#pragma unroll
        for (int ks = 0; ks < 2; ++ks)
            xifr[ks] = *reinterpret_cast<const bf16x8*>(
                xb + (size_t)(b0 + row) * EMB + i * 64 + ks * 32 + kg * 8);

        // xj (bf16) for this lane: batch col = b0+row, e = nt*16+kg*4+{0..3}
        ushort4 xjw[4];
#pragma unroll
        for (int nt = 0; nt < 4; ++nt)
            xjw[nt] = *reinterpret_cast<const ushort4*>(
                xb + (size_t)(b0 + row) * EMB + j * 64 + nt * 16 + kg * 4);

        f32x4 acc[4];
#pragma unroll
        for (int nt = 0; nt < 4; ++nt) {
            f32x4 z = {0.f, 0.f, 0.f, 0.f};
            acc[nt] = z;
            acc[nt] = __builtin_amdgcn_mfma_f32_16x16x32_bf16(wfr[nt][0], xifr[0], acc[nt], 0, 0, 0);
            acc[nt] = __builtin_amdgcn_mfma_f32_16x16x32_bf16(wfr[nt][1], xifr[1], acc[nt], 0, 0, 0);
        }

        // lane-local partial dot over its 16 e-values, then reduce over kg
        float v = 0.f;
#pragma unroll
        for (int nt = 0; nt < 4; ++nt) {
            v += (acc[nt][0] + bb[nt][0]) * bf2f(xjw[nt].x);
            v += (acc[nt][1] + bb[nt][1]) * bf2f(xjw[nt].y);
            v += (acc[nt][2] + bb[nt][2]) * bf2f(xjw[nt].z);
            v += (acc[nt][3] + bb[nt][3]) * bf2f(xjw[nt].w);
        }
        v += __shfl_xor(v, 16);
        v += __shfl_xor(v, 32);
        if (lane < 16)
            db[(size_t)(b0 + lane) * KPAD + p] = f2bf(v);
    }
}

// ---------- bilinear head via MFMA: out[:,2048:] = db @ Wot^T + bo ----------
__global__ __launch_bounds__(256) void k_bilin2(
        const ushort* __restrict__ db, const ushort* __restrict__ Wot,
        const float* __restrict__ bo, float* __restrict__ out) {
    int mt  = blockIdx.x >> 4;        // 16 m-tiles of 64
    int nt0 = blockIdx.x & 15;        // 16 n-tiles of 32
    int wave = threadIdx.x >> 6, lane = threadIdx.x & 63;
    int row = lane & 15, kg = lane >> 4;
    int m0 = mt * 64 + wave * 16;
    int n0 = nt0 * 32;

    f32x4 acc0 = {0.f, 0.f, 0.f, 0.f};
    f32x4 acc1 = {0.f, 0.f, 0.f, 0.f};
    const ushort* arow  = db  + (size_t)(m0 + row) * KPAD + kg * 8;
    const ushort* brow0 = Wot + (size_t)(n0 + row) * KPAD + kg * 8;
    const ushort* brow1 = brow0 + 16 * KPAD;
#pragma unroll
    for (int ks = 0; ks < 16; ++ks) {
        bf16x8 a  = *reinterpret_cast<const bf16x8*>(arow  + ks * 32);
        bf16x8 b0 = *reinterpret_cast<const bf16x8*>(brow0 + ks * 32);
        bf16x8 b1 = *reinterpret_cast<const bf16x8*>(brow1 + ks * 32);
        acc0 = __builtin_amdgcn_mfma_f32_16x16x32_bf16(a, b0, acc0, 0, 0, 0);
        acc1 = __builtin_amdgcn_mfma_f32_16x16x32_bf16(a, b1, acc1, 0, 0, 0);
    }
    int col = row;
    float bo0 = bo[n0 + col], bo1 = bo[n0 + 16 + col];
#pragma unroll
    for (int r = 0; r < 4; ++r) {
        size_t orow = (size_t)(m0 + kg * 4 + r) * OUT_STRIDE + 2048 + n0;
        out[orow + col]      = acc0[r] + bo0;
        out[orow + 16 + col] = acc1[r] + bo1;
    }
}

extern "C" void kernel_launch(void* const* d_in, const int* in_sizes, int n_in,
                              void* d_out, int out_size, void* d_ws, size_t ws_size,
                              hipStream_t stream) {
    const float* x    = (const float*)d_in[0];
    const float* W1   = (const float*)d_in[1];
    const float* b1   = (const float*)d_in[2];
    const float* W2   = (const float*)d_in[3];
    const float* b2   = (const float*)d_in[4];
    const float* ln_s = (const float*)d_in[5];
    const float* ln_b = (const float*)d_in[6];
    const float* Wp   = (const float*)d_in[7];
    const float* bp   = (const float*)d_in[8];
    const float* Wo   = (const float*)d_in[9];
    const float* bo   = (const float*)d_in[10];
    float* out = (float*)d_out;

    // workspace layout
    ushort* xb   = (ushort*)d_ws;                                        // 4,194,304 B
    ushort* wpt  = (ushort*)((char*)d_ws + 4194304);                     // 4,063,232 B
    ushort* db   = (ushort*)((char*)d_ws + 4194304 + 4063232);           // 1,048,576 B
    ushort* wot  = (ushort*)((char*)d_ws + 4194304 + 4063232 + 1048576); //   524,288 B

    k_prep<<<568, 256, 0, stream>>>(Wp, wpt, Wo, wot, db);
    k_senet<<<B_SZ / 4, 512, 0, stream>>>(x, xb, W1, b1, W2, b2, ln_s, ln_b, out);
    k_dots<<<P_PAIRS * 2, 256, 0, stream>>>(xb, wpt, bp, db);
    k_bilin2<<<256, 256, 0, stream>>>(db, wot, bo, out);
}

// Round 5
// 59.152 us; speedup vs baseline: 3.6027x; 1.0004x over previous
//
#include <hip/hip_runtime.h>
#include <hip/hip_bf16.h>

#define F_FEAT 32
#define D_DIM 64
#define B_SZ 1024
#define EMB 2048
#define P_PAIRS 496
#define KPAD 512
#define OUT_N 512
#define OUT_STRIDE 2560
#define LN_EPS 1e-6f

typedef __attribute__((ext_vector_type(8))) short bf16x8;
typedef __attribute__((ext_vector_type(4))) float f32x4;

__device__ inline ushort f2bf(float f) {
    union { float f; unsigned u; } a; a.f = f;
    unsigned u = a.u;
    unsigned r = (u + 0x7FFFu + ((u >> 16) & 1u)) >> 16;   // RTNE
    return (ushort)r;
}
__device__ inline float bf2f(ushort u) {
    union { unsigned u; float f; } a; a.u = ((unsigned)u) << 16;
    return a.f;
}

// ---------- prep (512 thr): cvt x | cvt+transpose Wp | cvt+transpose Wo | zero db pad ----
// blocks [0,512)      : x fp32 -> xb bf16, 8 elems/thread
// blocks [512,1008)   : Wp[p][d][e] -> Wpt[p][e][d] bf16 (LDS transpose)
// blocks [1008,1072)  : Wo[k][n] -> Wot[n][k] bf16, k padded to 512
// blocks [1072,1074)  : zero db[:, 496:512]
__global__ __launch_bounds__(512) void k_prep(
        const float* __restrict__ x, ushort* __restrict__ xb,
        const float* __restrict__ Wp, ushort* __restrict__ Wpt,
        const float* __restrict__ Wo, ushort* __restrict__ Wot,
        ushort* __restrict__ db) {
    __shared__ float tile[64][65];
    int t = threadIdx.x;
    int blk = blockIdx.x;

    if (blk < 512) {                        // ---- cvt x ----
        size_t base = ((size_t)blk * 512 + t) * 8;
        float4 v0 = *reinterpret_cast<const float4*>(x + base);
        float4 v1 = *reinterpret_cast<const float4*>(x + base + 4);
        bf16x8 o;
        o[0] = f2bf(v0.x); o[1] = f2bf(v0.y); o[2] = f2bf(v0.z); o[3] = f2bf(v0.w);
        o[4] = f2bf(v1.x); o[5] = f2bf(v1.y); o[6] = f2bf(v1.z); o[7] = f2bf(v1.w);
        *reinterpret_cast<bf16x8*>(xb + base) = o;
    } else if (blk < 1008) {                // ---- cvt+transpose Wp ----
        int p = blk - 512;
        const float* src = Wp + (size_t)p * 4096;
        ushort* dst = Wpt + (size_t)p * 4096;
#pragma unroll
        for (int it = 0; it < 2; ++it) {
            int d = it * 32 + (t >> 4);
            int e4 = (t & 15) * 4;
            float4 v = *reinterpret_cast<const float4*>(src + d * 64 + e4);
            tile[d][e4] = v.x; tile[d][e4 + 1] = v.y; tile[d][e4 + 2] = v.z; tile[d][e4 + 3] = v.w;
        }
        __syncthreads();
#pragma unroll
        for (int it = 0; it < 2; ++it) {
            int e = it * 32 + (t >> 4);
            int d4 = (t & 15) * 4;
            ushort4 o;
            o.x = f2bf(tile[d4][e]);     o.y = f2bf(tile[d4 + 1][e]);
            o.z = f2bf(tile[d4 + 2][e]); o.w = f2bf(tile[d4 + 3][e]);
            *reinterpret_cast<ushort4*>(dst + e * 64 + d4) = o;
        }
    } else if (blk < 1072) {                // ---- cvt+transpose Wo ----
        int bidx = blk - 1008;
        int k0 = (bidx & 7) * 64;
        int n0 = (bidx >> 3) * 64;
#pragma unroll
        for (int it = 0; it < 2; ++it) {
            int kr = it * 32 + (t >> 4);
            int nc = (t & 15) * 4;
            int k = k0 + kr;
            float4 v = {0.f, 0.f, 0.f, 0.f};
            if (k < P_PAIRS) v = *reinterpret_cast<const float4*>(Wo + (size_t)k * OUT_N + n0 + nc);
            tile[kr][nc] = v.x; tile[kr][nc + 1] = v.y; tile[kr][nc + 2] = v.z; tile[kr][nc + 3] = v.w;
        }
        __syncthreads();
#pragma unroll
        for (int it = 0; it < 2; ++it) {
            int nr = it * 32 + (t >> 4);
            int kc = (t & 15) * 4;
            ushort4 o;
            o.x = f2bf(tile[kc][nr]);     o.y = f2bf(tile[kc + 1][nr]);
            o.z = f2bf(tile[kc + 2][nr]); o.w = f2bf(tile[kc + 3][nr]);
            *reinterpret_cast<ushort4*>(Wot + (size_t)(n0 + nr) * KPAD + k0 + kc) = o;
        }
    } else {                                // ---- zero db pad cols ----
        int tid = (blk - 1072) * 512 + t;
        if (tid < B_SZ) {
            bf16x8 z = {0, 0, 0, 0, 0, 0, 0, 0};
            ushort* dstp = db + (size_t)tid * KPAD + P_PAIRS;
            *reinterpret_cast<bf16x8*>(dstp) = z;
            *reinterpret_cast<bf16x8*>(dstp + 8) = z;
        }
    }
}

// ---------- pair bilinear via transposed MFMA, bias folded into C-init ----------
// grid: 496 pairs x 2 half-batches. 4 waves x 8 tiles of 16 batch rows.
__global__ __launch_bounds__(256) void k_dots(
        const ushort* __restrict__ xb, const ushort* __restrict__ Wpt,
        const float* __restrict__ bp, ushort* __restrict__ db) {
    int p = blockIdx.x >> 1;
    int h = blockIdx.x & 1;
    int i = 0, rem = p;
    while (rem >= F_FEAT - 1 - i) { rem -= F_FEAT - 1 - i; ++i; }
    int j = i + 1 + rem;

    int wave = threadIdx.x >> 6, lane = threadIdx.x & 63;
    int row = lane & 15, kg = lane >> 4;   // row: e-row (A) / batch col (B,C)

    // A frags: Wp^T tile rows = e, k = d (loaded once, register-resident)
    bf16x8 wfr[4][2];
#pragma unroll
    for (int nt = 0; nt < 4; ++nt)
#pragma unroll
        for (int ks = 0; ks < 2; ++ks)
            wfr[nt][ks] = *reinterpret_cast<const bf16x8*>(
                Wpt + (size_t)p * 4096 + (nt * 16 + row) * 64 + ks * 32 + kg * 8);

    // bias bp[p][e] for this lane's e-indices: e = nt*16 + kg*4 + r
    f32x4 bb[4];
#pragma unroll
    for (int nt = 0; nt < 4; ++nt)
        bb[nt] = *reinterpret_cast<const f32x4*>(bp + p * 64 + nt * 16 + kg * 4);

#pragma unroll
    for (int it = 0; it < 8; ++it) {
        int b0 = h * 512 + (wave * 8 + it) * 16;

        // B frags: Xi^T, cols = batch (row), k = d
        bf16x8 xifr[2];
#pragma unroll
        for (int ks = 0; ks < 2; ++ks)
            xifr[ks] = *reinterpret_cast<const bf16x8*>(
                xb + (size_t)(b0 + row) * EMB + i * 64 + ks * 32 + kg * 8);

        // xj (bf16) for this lane: batch col = b0+row, e = nt*16+kg*4+{0..3}
        ushort4 xjw[4];
#pragma unroll
        for (int nt = 0; nt < 4; ++nt)
            xjw[nt] = *reinterpret_cast<const ushort4*>(
                xb + (size_t)(b0 + row) * EMB + j * 64 + nt * 16 + kg * 4);

        f32x4 acc[4];
#pragma unroll
        for (int nt = 0; nt < 4; ++nt) {
            acc[nt] = bb[nt];   // bias pre-folded into C
            acc[nt] = __builtin_amdgcn_mfma_f32_16x16x32_bf16(wfr[nt][0], xifr[0], acc[nt], 0, 0, 0);
            acc[nt] = __builtin_amdgcn_mfma_f32_16x16x32_bf16(wfr[nt][1], xifr[1], acc[nt], 0, 0, 0);
        }

        // lane-local partial dot over its 16 e-values, then reduce over kg
        float v = 0.f;
#pragma unroll
        for (int nt = 0; nt < 4; ++nt) {
            v += acc[nt][0] * bf2f(xjw[nt].x);
            v += acc[nt][1] * bf2f(xjw[nt].y);
            v += acc[nt][2] * bf2f(xjw[nt].z);
            v += acc[nt][3] * bf2f(xjw[nt].w);
        }
        v += __shfl_xor(v, 16);
        v += __shfl_xor(v, 32);
        if (lane < 16)
            db[(size_t)(b0 + lane) * KPAD + p] = f2bf(v);
    }
}

// ---------- fused tail: blocks [0,256) = SENet+LN ; blocks [256,384) = bilinear head ----
__global__ __launch_bounds__(512) void k_tail(
        const float* __restrict__ x,
        const float* __restrict__ W1, const float* __restrict__ b1,
        const float* __restrict__ W2, const float* __restrict__ b2,
        const float* __restrict__ ln_s, const float* __restrict__ ln_b,
        const ushort* __restrict__ db, const ushort* __restrict__ Wot,
        const float* __restrict__ bo, float* __restrict__ out) {
    __shared__ float xs[4][EMB];
    __shared__ float zs[4][128];
    __shared__ float a1s[4][32];
    __shared__ float red[2][4][8];
    int t = threadIdx.x;

    if (blockIdx.x >= 256) {
        // ---------------- bilinear head: m64 x n64 per block ----------------
        int bid = blockIdx.x - 256;        // 0..127
        int mt  = bid >> 3;                // 16 m-tiles of 64
        int nt0 = bid & 7;                 // 8 n-tiles of 64
        int wave = t >> 6, lane = t & 63;
        int row = lane & 15, kg = lane >> 4;
        int m0 = mt * 64 + (wave >> 1) * 16;
        int n0 = nt0 * 64 + (wave & 1) * 32;

        f32x4 acc0 = {0.f, 0.f, 0.f, 0.f};
        f32x4 acc1 = {0.f, 0.f, 0.f, 0.f};
        const ushort* arow  = db  + (size_t)(m0 + row) * KPAD + kg * 8;
        const ushort* brow0 = Wot + (size_t)(n0 + row) * KPAD + kg * 8;
        const ushort* brow1 = brow0 + 16 * KPAD;
#pragma unroll
        for (int ks = 0; ks < 16; ++ks) {
            bf16x8 a  = *reinterpret_cast<const bf16x8*>(arow  + ks * 32);
            bf16x8 b0 = *reinterpret_cast<const bf16x8*>(brow0 + ks * 32);
            bf16x8 b1 = *reinterpret_cast<const bf16x8*>(brow1 + ks * 32);
            acc0 = __builtin_amdgcn_mfma_f32_16x16x32_bf16(a, b0, acc0, 0, 0, 0);
            acc1 = __builtin_amdgcn_mfma_f32_16x16x32_bf16(a, b1, acc1, 0, 0, 0);
        }
        int col = row;
        float bo0 = bo[n0 + col], bo1 = bo[n0 + 16 + col];
#pragma unroll
        for (int r = 0; r < 4; ++r) {
            size_t orow = (size_t)(m0 + kg * 4 + r) * OUT_STRIDE + 2048 + n0;
            out[orow + col]      = acc0[r] + bo0;
            out[orow + 16 + col] = acc1[r] + bo1;
        }
        return;
    }

    // ---------------- SENet branch ----------------
    int b0 = blockIdx.x * 4;

    for (int r = 0; r < 4; ++r) {
        const float4* src = reinterpret_cast<const float4*>(x + (size_t)(b0 + r) * EMB);
        reinterpret_cast<float4*>(&xs[r][0])[t] = src[t];
    }
    __syncthreads();

    if (t < 256) {
        int r = t >> 6, f = (t >> 1) & 31, gg = t & 1;
        const float* base = &xs[r][f * 64 + gg * 32];
        float mx = -INFINITY, sm = 0.f;
        for (int q = 0; q < 32; ++q) {
            float v = base[(q + t) & 31];
            mx = fmaxf(mx, v); sm += v;
        }
        zs[r][f * 4 + gg]     = mx;
        zs[r][f * 4 + 2 + gg] = sm * (1.f / 32.f);
    }
    __syncthreads();

    if (t < 128) {
        int r = t >> 5, c = t & 31;
        float acc = b1[c];
        for (int k = 0; k < 128; ++k) acc += zs[r][k] * W1[k * 32 + c];
        a1s[r][c] = fmaxf(acc, 0.f);
    }
    __syncthreads();

    float acc[4][4];
#pragma unroll
    for (int r = 0; r < 4; ++r)
#pragma unroll
        for (int u = 0; u < 4; ++u) acc[r][u] = 0.f;

    for (int k = 0; k < 32; ++k) {
        float a0 = a1s[0][k], a1v = a1s[1][k], a2 = a1s[2][k], a3 = a1s[3][k];
#pragma unroll
        for (int u = 0; u < 4; ++u) {
            float wv = W2[k * EMB + t + 512 * u];
            acc[0][u] += a0 * wv; acc[1][u] += a1v * wv;
            acc[2][u] += a2 * wv; acc[3][u] += a3 * wv;
        }
    }
    float ssum[4], ssq[4];
#pragma unroll
    for (int r = 0; r < 4; ++r) { ssum[r] = 0.f; ssq[r] = 0.f; }
#pragma unroll
    for (int r = 0; r < 4; ++r) {
#pragma unroll
        for (int u = 0; u < 4; ++u) {
            int e = t + 512 * u;
            float w = acc[r][u] + b2[e];
            float s = xs[r][e] * (w + 1.0f);
            xs[r][e] = s;
            ssum[r] += s; ssq[r] += s * s;
        }
    }
    int lane = t & 63, w = t >> 6;
#pragma unroll
    for (int r = 0; r < 4; ++r) {
        float a = ssum[r], q = ssq[r];
        for (int off = 32; off; off >>= 1) { a += __shfl_down(a, off); q += __shfl_down(q, off); }
        if (lane == 0) { red[0][r][w] = a; red[1][r][w] = q; }
    }
    __syncthreads();
    float mu[4], rs[4];
#pragma unroll
    for (int r = 0; r < 4; ++r) {
        float a = 0.f, q = 0.f;
#pragma unroll
        for (int i = 0; i < 8; ++i) { a += red[0][r][i]; q += red[1][r][i]; }
        mu[r] = a * (1.f / 2048.f);
        float var = q * (1.f / 2048.f) - mu[r] * mu[r];
        rs[r] = rsqrtf(var + LN_EPS);
    }
#pragma unroll
    for (int r = 0; r < 4; ++r) {
#pragma unroll
        for (int u = 0; u < 4; ++u) {
            int e = t + 512 * u;
            float s = xs[r][e];
            out[(size_t)(b0 + r) * OUT_STRIDE + e] = (s - mu[r]) * rs[r] * ln_s[e] + ln_b[e];
        }
    }
}

extern "C" void kernel_launch(void* const* d_in, const int* in_sizes, int n_in,
                              void* d_out, int out_size, void* d_ws, size_t ws_size,
                              hipStream_t stream) {
    const float* x    = (const float*)d_in[0];
    const float* W1   = (const float*)d_in[1];
    const float* b1   = (const float*)d_in[2];
    const float* W2   = (const float*)d_in[3];
    const float* b2   = (const float*)d_in[4];
    const float* ln_s = (const float*)d_in[5];
    const float* ln_b = (const float*)d_in[6];
    const float* Wp   = (const float*)d_in[7];
    const float* bp   = (const float*)d_in[8];
    const float* Wo   = (const float*)d_in[9];
    const float* bo   = (const float*)d_in[10];
    float* out = (float*)d_out;

    // workspace layout
    ushort* xb   = (ushort*)d_ws;                                        // 4,194,304 B
    ushort* wpt  = (ushort*)((char*)d_ws + 4194304);                     // 4,063,232 B
    ushort* db   = (ushort*)((char*)d_ws + 4194304 + 4063232);           // 1,048,576 B
    ushort* wot  = (ushort*)((char*)d_ws + 4194304 + 4063232 + 1048576); //   524,288 B

    k_prep<<<1074, 512, 0, stream>>>(x, xb, Wp, wpt, Wo, wot, db);
    k_dots<<<P_PAIRS * 2, 256, 0, stream>>>(xb, wpt, bp, db);
    k_tail<<<384, 512, 0, stream>>>(x, W1, b1, W2, b2, ln_s, ln_b, db, wot, bo, out);
}